// Round 22
// baseline (88.636 us; speedup 1.0000x reference)
//
#include <hip/hip_runtime.h>
#include <hip/hip_bf16.h>
#include <stdint.h>

#define B_ 16
#define S_ 2048
#define D_ 512
#define A_ 512
#define M_TOT (B_ * S_)

typedef __attribute__((ext_vector_type(4))) float f32x4;
typedef __attribute__((ext_vector_type(8))) short bf16x8;

__device__ inline unsigned short f2bf(float f) {
  union { float f; unsigned int u; } c; c.f = f;
  unsigned int u = c.u;
  unsigned int r = (u + 0x7fffu + ((u >> 16) & 1u)) >> 16;  // RNE
  return (unsigned short)r;
}

__device__ inline unsigned pk2bf(float x, float y) {
  __hip_bfloat162 p = __float22bfloat162_rn(float2{x, y});
  union { __hip_bfloat162 h; unsigned u; } c; c.h = p;
  return c.u;
}

__device__ inline float fast_tanh(float x) {
  float e = __expf(2.0f * x);
  return 1.0f - 2.0f * __builtin_amdgcn_rcpf(e + 1.0f);
}

__device__ inline void gload_lds16(const void* g, void* l) {
  __builtin_amdgcn_global_load_lds((const __attribute__((address_space(1))) void*)g,
                                   (__attribute__((address_space(3))) void*)l, 16, 0, 0);
}

// ---------------------------------------------------------------------------
// K0: pack [Wq;Wk] (each [512,512] f32, row=d, col=a) into WT bf16
// [A=512][Kcat=1024] (row=a, col=d-concat), i.e. B^T layout for the GEMM.
// ---------------------------------------------------------------------------
__global__ __launch_bounds__(256) void k0_pack_w(const float* __restrict__ Wq,
                                                 const float* __restrict__ Wk,
                                                 unsigned short* __restrict__ WT) {
  __shared__ unsigned short tile[64][65];
  int bid = blockIdx.x;
  int dt = bid & 15, at = bid >> 4;
  int d0 = dt * 64, a0 = at * 64;
  int t = threadIdx.x;
  int col = t & 63, rbase = t >> 6;
#pragma unroll
  for (int r8 = 0; r8 < 16; ++r8) {
    int row = r8 * 4 + rbase;
    int dcat = d0 + row;
    float f = (dcat < 512) ? Wq[(size_t)dcat * 512 + a0 + col]
                           : Wk[(size_t)(dcat - 512) * 512 + a0 + col];
    tile[row][col] = f2bf(f);
  }
  __syncthreads();
#pragma unroll
  for (int r8 = 0; r8 < 16; ++r8) {
    int arow = r8 * 4 + rbase;
    WT[(size_t)(a0 + arow) * 1024 + d0 + col] = tile[col][arow];
  }
}

// ---------------------------------------------------------------------------
// K1: scores partial — r10 schedule VERBATIM, geometry BM=256 x BN=256
// (cb = half of A=512). Rationale (byte-service model, r18/r21 evidence):
// phase time ~ staged-bytes/CU; BM=256/BN=256 HALVES B-DMA per phase
// (32->16 KB; total B 256->128 MiB) at IDENTICAL MFMA/phase, wave-tile
// (128x64), ds_read count, and LDS-read traffic. A-vec doubles (cheap:
// VALUBusy 15%). LDS 64 KiB, grid 256 = 1 block/CU (the proven regime).
// Counted-vmcnt pipeline: phase p: stageB(p+1) [2 DMA] | issueA(p+2)->regs
// [4 vec] | frags(p) | 32 MFMA | writeA(p+1) (write-late) | vmcnt(4)
// lgkm(0) [drain DMAs, keep the 4 A-vec loads] | s_barrier.
// XCD-paired decode: both cb of a strip share an XCD (A re-read L2-hot).
// LDS swizzle: 64B rows, 4x16B chunks, chunk' = chunk ^ ((row>>1)&3).
// ---------------------------------------------------------------------------
__global__ __launch_bounds__(512, 2) void k1_scores(
    const float* __restrict__ Q, const float* __restrict__ K,
    const unsigned short* __restrict__ WT, const float* __restrict__ Wsv,
    float* __restrict__ partial) {
  __shared__ unsigned short Al[2][256 * 32];   // 2 x 16 KiB
  __shared__ unsigned short Bl[2][256 * 32];   // 2 x 16 KiB

  const int t = threadIdx.x;
  const int lane = t & 63, w = t >> 6;
  const int frow = lane & 15, fsl = lane >> 4;
  const int wr = w >> 2, wc = w & 3;           // 2M x 4N wave grid

  const int bid = (int)blockIdx.x;
  const int wg = (bid & 7) * 32 + (bid >> 3);  // bijective (256 % 8 == 0)
  const int strip = wg >> 1, cb = wg & 1;      // cb pair -> same XCD
  const int row0 = strip * 256, col0 = cb * 256;

  // A staging: 2 threads/row; thread covers row ar, chunks ac0, ac0+1
  // (16 fp32 -> 16 bf16 = 2 x 16B chunks).
  const int ar = t >> 1, ac0 = (t & 1) * 2;
  const int ab0 = ar * 64 + (((ac0 + 0) ^ ((ar >> 1) & 3)) * 16);
  const int ab1 = ar * 64 + (((ac0 + 1) ^ ((ar >> 1) & 3)) * 16);

  float4 rP[4], rQr[4];                        // two named A-load sets

  auto issueA = [&](int p, float4* r) {
    const float* src = (p < 16) ? Q : K;
    const float* ap = src + (size_t)(row0 + ar) * 512 + ((p * 32) & 511) + ac0 * 8;
    r[0] = *(const float4*)(ap + 0);
    r[1] = *(const float4*)(ap + 4);
    r[2] = *(const float4*)(ap + 8);
    r[3] = *(const float4*)(ap + 12);
  };
  auto writeA = [&](const float4* r, int buf) {
    uint4 d0, d1;
    d0.x = pk2bf(r[0].x, r[0].y); d0.y = pk2bf(r[0].z, r[0].w);
    d0.z = pk2bf(r[1].x, r[1].y); d0.w = pk2bf(r[1].z, r[1].w);
    d1.x = pk2bf(r[2].x, r[2].y); d1.y = pk2bf(r[2].z, r[2].w);
    d1.z = pk2bf(r[3].x, r[3].y); d1.w = pk2bf(r[3].z, r[3].w);
    *(uint4*)((char*)&Al[buf][0] + ab0) = d0;
    *(uint4*)((char*)&Al[buf][0] + ab1) = d1;
  };
  auto stageB = [&](int p, int buf) {
#pragma unroll
    for (int q = 0; q < 2; ++q) {
      int pc = (w * 2 + q) * 64 + lane;        // 16B-chunk index 0..1023
      int row = pc >> 2;                       // local B row 0..255
      int sl = (pc & 3) ^ ((row >> 1) & 3);    // inverse-swizzled source slot
      const char* g = (const char*)WT + (size_t)(col0 + row) * 2048 + p * 64 + sl * 16;
      gload_lds16(g, (char*)&Bl[buf][0] + (size_t)(w * 2 + q) * 1024);
    }
  };

  f32x4 acc[8][4];
#pragma unroll
  for (int m = 0; m < 8; ++m)
#pragma unroll
    for (int n = 0; n < 4; ++n) acc[m][n] = (f32x4){0.f, 0.f, 0.f, 0.f};

  const int ch = (fsl ^ ((frow >> 1) & 3)) * 16;

  auto doMfma = [&](int CUR) {
    bf16x8 af[8], bfr[4];
#pragma unroll
    for (int m = 0; m < 8; ++m) {
      int r = wr * 128 + m * 16 + frow;
      af[m] = *(const bf16x8*)((const char*)&Al[CUR][0] + r * 64
                               + ((fsl ^ ((r >> 1) & 3)) * 16));
    }
#pragma unroll
    for (int n = 0; n < 4; ++n) {
      int r = wc * 64 + n * 16 + frow;
      bfr[n] = *(const bf16x8*)((const char*)&Bl[CUR][0] + r * 64
                                + ((fsl ^ ((r >> 1) & 3)) * 16));
    }
    __builtin_amdgcn_s_setprio(1);
#pragma unroll
    for (int m = 0; m < 8; ++m)
#pragma unroll
      for (int n = 0; n < 4; ++n)
        acc[m][n] = __builtin_amdgcn_mfma_f32_16x16x32_bf16(af[m], bfr[n], acc[m][n], 0, 0, 0);
    __builtin_amdgcn_s_setprio(0);
  };

  // ---- prologue: tile 0 staged; A(1) left in flight across the barrier ----
  issueA(0, rP);
  stageB(0, 0);
  __builtin_amdgcn_sched_barrier(0);
  issueA(1, rQr);
  writeA(rP, 0);                        // compiler waits only the A(0) loads
  asm volatile("s_waitcnt vmcnt(4) lgkmcnt(0)" ::: "memory");  // drain B(0)
  __builtin_amdgcn_s_barrier();

  // ---- main loop: phases 0..29 ----
  auto phase = [&](int p, int CUR, float4* rCur, const float4* rNext) {
    stageB(p + 1, CUR ^ 1);
    __builtin_amdgcn_sched_barrier(0);
    issueA(p + 2, rCur);
    doMfma(CUR);
    writeA(rNext, CUR ^ 1);             // A(p+1), write-late
    asm volatile("s_waitcnt vmcnt(4) lgkmcnt(0)" ::: "memory");
    __builtin_amdgcn_s_barrier();
  };

  for (int kt2 = 0; kt2 < 15; ++kt2) {
    phase(2 * kt2 + 0, 0, rP, rQr);
    phase(2 * kt2 + 1, 1, rQr, rP);
  }

  // ---- peeled tail: phase 30 (no A issue), phase 31 (compute only) ----
  stageB(31, 1);
  doMfma(0);
  writeA(rQr, 1);                       // A(31)
  asm volatile("s_waitcnt vmcnt(0) lgkmcnt(0)" ::: "memory");
  __builtin_amdgcn_s_barrier();
  doMfma(1);

  // ---- epilogue: tanh * Ws, reduce over this block's 256 cols ----
  float wsv[4];
#pragma unroll
  for (int n = 0; n < 4; ++n) wsv[n] = Wsv[col0 + wc * 64 + n * 16 + frow];
  __syncthreads();                      // safe to alias Al for scw
  float* scw = (float*)&Al[0][0];       // [4][256] = 4 KiB
#pragma unroll
  for (int m = 0; m < 8; ++m) {
#pragma unroll
    for (int ii = 0; ii < 4; ++ii) {
      float s = 0.f;
#pragma unroll
      for (int n = 0; n < 4; ++n)
        s += fast_tanh(acc[m][n][ii]) * wsv[n];
      s += __shfl_xor(s, 1);
      s += __shfl_xor(s, 2);
      s += __shfl_xor(s, 4);
      s += __shfl_xor(s, 8);
      if (frow == 0)
        scw[wc * 256 + wr * 128 + m * 16 + fsl * 4 + ii] = s;
    }
  }
  __syncthreads();
  if (t < 256) {
    float s = scw[t] + scw[256 + t] + scw[512 + t] + scw[768 + t];
    partial[(size_t)cb * M_TOT + row0 + t] = s;
  }
}

// ---------------------------------------------------------------------------
// K3 (fused softmax + V-weighted sum): block (dh, sc, b) re-derives the
// batch softmax from the two L2-hot partial rows, then computes
// upart[sc][b][dh-half]; dh==0 blocks write outw.
// ---------------------------------------------------------------------------
__global__ __launch_bounds__(256) void k3_vsum(const float* __restrict__ value,
                                               const float* __restrict__ partial,
                                               float* __restrict__ upart,
                                               float* __restrict__ outw) {
  int bid = blockIdx.x;
  int dh = bid & 1, sc = (bid >> 1) & 15, b = bid >> 5;
  int t = threadIdx.x;
  int lane = t & 63, wave = t >> 6;
  int dg = t & 63, sg = t >> 6;
  __shared__ float red[4], red2[4];
  __shared__ float wl[128];
  __shared__ f32x4 redv[4][64];

  float v[8];
  float mx = -1e30f;
#pragma unroll
  for (int e = 0; e < 8; ++e) {
    size_t o = (size_t)b * S_ + e * 256 + t;
    float p = partial[o] + partial[M_TOT + o];
    v[e] = p;
    mx = fmaxf(mx, p);
  }
  for (int off = 1; off < 64; off <<= 1) mx = fmaxf(mx, __shfl_xor(mx, off));
  if (lane == 0) red[wave] = mx;
  __syncthreads();
  mx = fmaxf(fmaxf(red[0], red[1]), fmaxf(red[2], red[3]));
  float sum = 0.f;
#pragma unroll
  for (int e = 0; e < 8; ++e) sum += expf(v[e] - mx);
  for (int off = 1; off < 64; off <<= 1) sum += __shfl_xor(sum, off);
  if (lane == 0) red2[wave] = sum;
  __syncthreads();
  sum = red2[0] + red2[1] + red2[2] + red2[3];
  float inv = 1.f / sum;

  int s0 = sc * 128;
  if (t < 128) {
    size_t o = (size_t)b * S_ + s0 + t;
    float ww = expf(partial[o] + partial[M_TOT + o] - mx) * inv;
    wl[t] = ww;
    if (dh == 0) outw[o] = ww;
  }
  __syncthreads();

  const float* vp = value + ((size_t)b * S_ + s0) * 512 + dh * 256 + dg * 4;
  f32x4 a = (f32x4){0.f, 0.f, 0.f, 0.f};
  for (int s = sg; s < 128; s += 4) {
    float4 v4 = *(const float4*)(vp + (size_t)s * 512);
    float ws = wl[s];
    a[0] += ws * v4.x; a[1] += ws * v4.y; a[2] += ws * v4.z; a[3] += ws * v4.w;
  }
  redv[sg][dg] = a;
  __syncthreads();
  if (sg == 0) {
    f32x4 r = redv[0][dg] + redv[1][dg] + redv[2][dg] + redv[3][dg];
    float* dst = upart + (size_t)(sc * 16 + b) * 512 + dh * 256 + dg * 4;
    dst[0] = r[0]; dst[1] = r[1]; dst[2] = r[2]; dst[3] = r[3];
  }
}

// ---------------------------------------------------------------------------
// K4: context[b,a] = sum_d u[b,d] * Wv[d,a]. fp32. 64 blocks.
// ---------------------------------------------------------------------------
__global__ __launch_bounds__(256) void k4_ctx(const float* __restrict__ upart,
                                              const float* __restrict__ Wv,
                                              float* __restrict__ out) {
  int b = blockIdx.x >> 2, q = blockIdx.x & 3;
  int t = threadIdx.x;
  int col = q * 128 + (t & 127), dhf = t >> 7;
  __shared__ float ul[512];
  __shared__ float part[2][128];
  for (int i = t; i < 512; i += 256) {
    float u = 0.f;
#pragma unroll
    for (int c = 0; c < 16; ++c) u += upart[(size_t)(c * 16 + b) * 512 + i];
    ul[i] = u;
  }
  __syncthreads();
  float acc = 0.f;
#pragma unroll 8
  for (int d = dhf * 256; d < dhf * 256 + 256; ++d)
    acc += ul[d] * Wv[(size_t)d * 512 + col];
  part[dhf][t & 127] = acc;
  __syncthreads();
  if (dhf == 0)
    out[(size_t)b * 512 + col] = part[0][t & 127] + part[1][t & 127];
}

// ---------------------------------------------------------------------------
extern "C" void kernel_launch(void* const* d_in, const int* in_sizes, int n_in,
                              void* d_out, int out_size, void* d_ws, size_t ws_size,
                              hipStream_t stream) {
  const float* Q  = (const float*)d_in[0];
  const float* Kk = (const float*)d_in[1];
  const float* V  = (const float*)d_in[2];
  const float* Wq = (const float*)d_in[3];
  const float* Wk = (const float*)d_in[4];
  const float* Wv = (const float*)d_in[5];
  const float* Ws = (const float*)d_in[6];
  float* out = (float*)d_out;

  char* ws = (char*)d_ws;
  unsigned short* WT = (unsigned short*)ws;                        // 1 MiB
  float* partial = (float*)(ws + (1 << 20));                       // 256 KiB: [2][32768]
  float* upart   = (float*)(ws + (1 << 20) + (512 << 10));         // 512 KiB

  float* outw = out + B_ * A_;   // attention weights region [B*S]

  k0_pack_w<<<dim3(128), dim3(256), 0, stream>>>(Wq, Wk, WT);
  k1_scores<<<dim3(256), dim3(512), 0, stream>>>(Q, Kk, WT, Ws, partial);
  k3_vsum<<<dim3(512), dim3(256), 0, stream>>>(V, partial, upart, outw);
  k4_ctx<<<dim3(64), dim3(256), 0, stream>>>(upart, Wv, out);
}

// Round 23
// 85.189 us; speedup vs baseline: 1.0405x; 1.0405x over previous
//
#include <hip/hip_runtime.h>
#include <hip/hip_bf16.h>
#include <stdint.h>

#define B_ 16
#define S_ 2048
#define D_ 512
#define A_ 512

typedef __attribute__((ext_vector_type(4))) float f32x4;
typedef __attribute__((ext_vector_type(8))) short bf16x8;

__device__ inline unsigned short f2bf(float f) {
  union { float f; unsigned int u; } c; c.f = f;
  unsigned int u = c.u;
  unsigned int r = (u + 0x7fffu + ((u >> 16) & 1u)) >> 16;  // RNE
  return (unsigned short)r;
}

__device__ inline unsigned pk2bf(float x, float y) {
  __hip_bfloat162 p = __float22bfloat162_rn(float2{x, y});
  union { __hip_bfloat162 h; unsigned u; } c; c.h = p;
  return c.u;
}

__device__ inline float fast_tanh(float x) {
  float e = __expf(2.0f * x);
  return 1.0f - 2.0f * __builtin_amdgcn_rcpf(e + 1.0f);
}

__device__ inline void gload_lds16(const void* g, void* l) {
  __builtin_amdgcn_global_load_lds((const __attribute__((address_space(1))) void*)g,
                                   (__attribute__((address_space(3))) void*)l, 16, 0, 0);
}

// ---------------------------------------------------------------------------
// K0: pack [Wq;Wk] (each [512,512] f32, row=d, col=a) into WT bf16
// [A=512][Kcat=1024] (row=a, col=d-concat), i.e. B^T layout for the GEMM.
// ---------------------------------------------------------------------------
__global__ __launch_bounds__(256) void k0_pack_w(const float* __restrict__ Wq,
                                                 const float* __restrict__ Wk,
                                                 unsigned short* __restrict__ WT) {
  __shared__ unsigned short tile[64][65];
  int bid = blockIdx.x;
  int dt = bid & 15, at = bid >> 4;
  int d0 = dt * 64, a0 = at * 64;
  int t = threadIdx.x;
  int col = t & 63, rbase = t >> 6;
#pragma unroll
  for (int r8 = 0; r8 < 16; ++r8) {
    int row = r8 * 4 + rbase;
    int dcat = d0 + row;
    float f = (dcat < 512) ? Wq[(size_t)dcat * 512 + a0 + col]
                           : Wk[(size_t)(dcat - 512) * 512 + a0 + col];
    tile[row][col] = f2bf(f);
  }
  __syncthreads();
#pragma unroll
  for (int r8 = 0; r8 < 16; ++r8) {
    int arow = r8 * 4 + rbase;
    WT[(size_t)(a0 + arow) * 1024 + d0 + col] = tile[col][arow];
  }
}

// ---------------------------------------------------------------------------
// K1: scores — r10 config VERBATIM (confirmed optimum: 66.5-69.5 us across
// 4 independent rounds; 21 single-variable deviations all regressed).
// BM=128, BN=512 (full N), BK=32, 32 phases, 512 threads = 8 waves,
// wave-tile 128x64 (8x4 frags, acc=128). Counted-vmcnt pipeline:
//   phase p: stageB(p+1) gloads | issueA(p+2)->regs | frags(p) | 32 MFMA |
//            writeA(p+1) (write-late) | vmcnt(2) lgkm(0) | s_barrier
// A-loads survive the barrier (2 in flight); B gloads get a full MFMA phase
// of cover. A converted via v_cvt_pk_bf16_f32. Tail phases 30/31 peeled.
// LDS swizzle: 64B rows, 4x16B chunks, chunk' = chunk ^ ((row>>1)&3).
// Structural note: 517 TF on M=32768/N=512/K=1024 ~= the 2-barrier-structure
// ceiling for this shape (m233: 607 TF at ideal 4096^3 amortization; our
// K gives 4x fewer phases to amortize). Deeper pipelines (m201 8-phase)
// need K-depth this shape lacks (r11 regression confirmed).
// ---------------------------------------------------------------------------
__global__ __launch_bounds__(512, 2) void k1_scores(
    const float* __restrict__ Q, const float* __restrict__ K,
    const unsigned short* __restrict__ WT, const float* __restrict__ Wsv,
    float* __restrict__ score) {
  __shared__ unsigned short Al[2][128 * 32];   // 2 x 8 KiB
  __shared__ unsigned short Bl[2][512 * 32];   // 2 x 32 KiB

  const int t = threadIdx.x;
  const int lane = t & 63, w = t >> 6;
  const int frow = lane & 15, fsl = lane >> 4;
  const int row0 = (int)blockIdx.x * 128;

  // A staging: thread handles row ar, 8 floats at cols ak..ak+7 (one 16B chunk)
  const int ar = t >> 2, ak = (t & 3) * 8;
  const int abyte = ar * 64 + (((t & 3) ^ ((ar >> 1) & 3)) * 16);

  float4 rA0[2], rA1[2];

  auto issueA = [&](int p, float4* r) {
    const float* src = (p < 16) ? Q : K;
    const float* ap = src + (size_t)(row0 + ar) * 512 + ((p * 32) & 511) + ak;
    r[0] = *(const float4*)(ap);
    r[1] = *(const float4*)(ap + 4);
  };
  auto writeA = [&](const float4* r, int buf) {
    uint4 d;
    d.x = pk2bf(r[0].x, r[0].y);
    d.y = pk2bf(r[0].z, r[0].w);
    d.z = pk2bf(r[1].x, r[1].y);
    d.w = pk2bf(r[1].z, r[1].w);
    *(uint4*)((char*)&Al[buf][0] + abyte) = d;
  };
  auto stageB = [&](int p, int buf) {
#pragma unroll
    for (int q = 0; q < 4; ++q) {
      int pc = (w * 4 + q) * 64 + lane;        // 16B-chunk index
      int row = pc >> 2;
      int sl = (pc & 3) ^ ((row >> 1) & 3);    // inverse-swizzled source slot
      const char* g = (const char*)WT + (size_t)row * 2048 + p * 64 + sl * 16;
      gload_lds16(g, (char*)&Bl[buf][0] + (size_t)(w * 4 + q) * 1024);
    }
  };

  f32x4 acc[8][4];
#pragma unroll
  for (int m = 0; m < 8; ++m)
#pragma unroll
    for (int n = 0; n < 4; ++n) acc[m][n] = (f32x4){0.f, 0.f, 0.f, 0.f};

  const int ch = (fsl ^ ((frow >> 1) & 3)) * 16;

  auto doMfma = [&](int CUR) {
    bf16x8 af[8], bfr[4];
#pragma unroll
    for (int m = 0; m < 8; ++m)
      af[m] = *(const bf16x8*)((const char*)&Al[CUR][0] + (m * 16 + frow) * 64 + ch);
#pragma unroll
    for (int n = 0; n < 4; ++n)
      bfr[n] = *(const bf16x8*)((const char*)&Bl[CUR][0] + (w * 64 + n * 16 + frow) * 64 + ch);
    __builtin_amdgcn_s_setprio(1);
#pragma unroll
    for (int m = 0; m < 8; ++m)
#pragma unroll
      for (int n = 0; n < 4; ++n)
        acc[m][n] = __builtin_amdgcn_mfma_f32_16x16x32_bf16(af[m], bfr[n], acc[m][n], 0, 0, 0);
    __builtin_amdgcn_s_setprio(0);
  };

  // ---- prologue: tile 0 staged; A(1) left in flight across the barrier ----
  issueA(0, rA0);
  stageB(0, 0);
  __builtin_amdgcn_sched_barrier(0);
  issueA(1, rA1);
  writeA(rA0, 0);                       // compiler waits its own A(0) loads
  asm volatile("s_waitcnt vmcnt(2) lgkmcnt(0)" ::: "memory");
  __builtin_amdgcn_s_barrier();

  // ---- main loop: phases 0..29 ----
  auto phase = [&](int p, int CUR, float4* rCur, const float4* rNext) {
    stageB(p + 1, CUR ^ 1);
    __builtin_amdgcn_sched_barrier(0);
    issueA(p + 2, rCur);
    doMfma(CUR);
    writeA(rNext, CUR ^ 1);             // A(p+1), write-late
    asm volatile("s_waitcnt vmcnt(2) lgkmcnt(0)" ::: "memory");
    __builtin_amdgcn_s_barrier();
  };

  for (int kt2 = 0; kt2 < 15; ++kt2) {
    phase(2 * kt2 + 0, 0, rA0, rA1);
    phase(2 * kt2 + 1, 1, rA1, rA0);
  }

  // ---- peeled tail: phase 30 (no A issue), phase 31 (compute only) ----
  stageB(31, 1);
  doMfma(0);
  writeA(rA1, 1);                       // A(31)
  asm volatile("s_waitcnt vmcnt(0) lgkmcnt(0)" ::: "memory");
  __builtin_amdgcn_s_barrier();
  doMfma(1);

  // ---- epilogue: tanh * Ws, reduce over all 512 cols ----
  float wsv[4];
#pragma unroll
  for (int n = 0; n < 4; ++n) wsv[n] = Wsv[w * 64 + n * 16 + frow];
  __syncthreads();                      // safe to alias Al for scw
  float* scw = (float*)&Al[0][0];       // [8][128]
#pragma unroll
  for (int m = 0; m < 8; ++m) {
#pragma unroll
    for (int ii = 0; ii < 4; ++ii) {
      float s = 0.f;
#pragma unroll
      for (int n = 0; n < 4; ++n)
        s += fast_tanh(acc[m][n][ii]) * wsv[n];
      s += __shfl_xor(s, 1);
      s += __shfl_xor(s, 2);
      s += __shfl_xor(s, 4);
      s += __shfl_xor(s, 8);
      if (frow == 0) scw[w * 128 + m * 16 + fsl * 4 + ii] = s;
    }
  }
  __syncthreads();
  if (t < 128) {
    float s = 0.f;
#pragma unroll
    for (int ww = 0; ww < 8; ++ww) s += scw[ww * 128 + t];
    score[row0 + t] = s;
  }
}

// ---------------------------------------------------------------------------
// K3 (fused softmax + V-weighted sum): block (dh, sc, b) re-derives the
// batch softmax from the L2-hot score row, then computes
// upart[sc][b][dh-half]; dh==0 blocks write outw. V read = 64 MB ~ HBM floor.
// ---------------------------------------------------------------------------
__global__ __launch_bounds__(256) void k3_vsum(const float* __restrict__ value,
                                               const float* __restrict__ score,
                                               float* __restrict__ upart,
                                               float* __restrict__ outw) {
  int bid = blockIdx.x;
  int dh = bid & 1, sc = (bid >> 1) & 15, b = bid >> 5;
  int t = threadIdx.x;
  int lane = t & 63, wave = t >> 6;
  int dg = t & 63, sg = t >> 6;
  __shared__ float red[4], red2[4];
  __shared__ float wl[128];
  __shared__ f32x4 redv[4][64];

  float v[8];
  float mx = -1e30f;
#pragma unroll
  for (int e = 0; e < 8; ++e) {
    float p = score[(size_t)b * S_ + e * 256 + t];
    v[e] = p;
    mx = fmaxf(mx, p);
  }
  for (int off = 1; off < 64; off <<= 1) mx = fmaxf(mx, __shfl_xor(mx, off));
  if (lane == 0) red[wave] = mx;
  __syncthreads();
  mx = fmaxf(fmaxf(red[0], red[1]), fmaxf(red[2], red[3]));
  float sum = 0.f;
#pragma unroll
  for (int e = 0; e < 8; ++e) sum += expf(v[e] - mx);
  for (int off = 1; off < 64; off <<= 1) sum += __shfl_xor(sum, off);
  if (lane == 0) red2[wave] = sum;
  __syncthreads();
  sum = red2[0] + red2[1] + red2[2] + red2[3];
  float inv = 1.f / sum;

  int s0 = sc * 128;
  if (t < 128) {
    size_t o = (size_t)b * S_ + s0 + t;
    float ww = expf(score[o] - mx) * inv;
    wl[t] = ww;
    if (dh == 0) outw[o] = ww;
  }
  __syncthreads();

  const float* vp = value + ((size_t)b * S_ + s0) * 512 + dh * 256 + dg * 4;
  f32x4 a = (f32x4){0.f, 0.f, 0.f, 0.f};
  for (int s = sg; s < 128; s += 4) {
    float4 v4 = *(const float4*)(vp + (size_t)s * 512);
    float ws = wl[s];
    a[0] += ws * v4.x; a[1] += ws * v4.y; a[2] += ws * v4.z; a[3] += ws * v4.w;
  }
  redv[sg][dg] = a;
  __syncthreads();
  if (sg == 0) {
    f32x4 r = redv[0][dg] + redv[1][dg] + redv[2][dg] + redv[3][dg];
    float* dst = upart + (size_t)(sc * 16 + b) * 512 + dh * 256 + dg * 4;
    dst[0] = r[0]; dst[1] = r[1]; dst[2] = r[2]; dst[3] = r[3];
  }
}

// ---------------------------------------------------------------------------
// K4: context[b,a] = sum_d u[b,d] * Wv[d,a]. fp32. 64 blocks.
// ---------------------------------------------------------------------------
__global__ __launch_bounds__(256) void k4_ctx(const float* __restrict__ upart,
                                              const float* __restrict__ Wv,
                                              float* __restrict__ out) {
  int b = blockIdx.x >> 2, q = blockIdx.x & 3;
  int t = threadIdx.x;
  int col = q * 128 + (t & 127), dhf = t >> 7;
  __shared__ float ul[512];
  __shared__ float part[2][128];
  for (int i = t; i < 512; i += 256) {
    float u = 0.f;
#pragma unroll
    for (int c = 0; c < 16; ++c) u += upart[(size_t)(c * 16 + b) * 512 + i];
    ul[i] = u;
  }
  __syncthreads();
  float acc = 0.f;
#pragma unroll 8
  for (int d = dhf * 256; d < dhf * 256 + 256; ++d)
    acc += ul[d] * Wv[(size_t)d * 512 + col];
  part[dhf][t & 127] = acc;
  __syncthreads();
  if (dhf == 0)
    out[(size_t)b * 512 + col] = part[0][t & 127] + part[1][t & 127];
}

// ---------------------------------------------------------------------------
extern "C" void kernel_launch(void* const* d_in, const int* in_sizes, int n_in,
                              void* d_out, int out_size, void* d_ws, size_t ws_size,
                              hipStream_t stream) {
  const float* Q  = (const float*)d_in[0];
  const float* Kk = (const float*)d_in[1];
  const float* V  = (const float*)d_in[2];
  const float* Wq = (const float*)d_in[3];
  const float* Wk = (const float*)d_in[4];
  const float* Wv = (const float*)d_in[5];
  const float* Ws = (const float*)d_in[6];
  float* out = (float*)d_out;

  char* ws = (char*)d_ws;
  unsigned short* WT = (unsigned short*)ws;                        // 1 MiB
  float* score = (float*)(ws + (1 << 20));                         // 128 KiB
  float* upart = (float*)(ws + (1 << 20) + (512 << 10));           // 512 KiB

  float* outw = out + B_ * A_;   // attention weights region [B*S]

  k0_pack_w<<<dim3(128), dim3(256), 0, stream>>>(Wq, Wk, WT);
  k1_scores<<<dim3(256), dim3(512), 0, stream>>>(Q, Kk, WT, Ws, score);
  k3_vsum<<<dim3(512), dim3(256), 0, stream>>>(V, score, upart, outw);
  k4_ctx<<<dim3(64), dim3(256), 0, stream>>>(upart, Wv, out);
}